// Round 1
// baseline (541.906 us; speedup 1.0000x reference)
//
#include <hip/hip_runtime.h>

// S4 layer, MI355X. B=16, T=2048, H=1024, N=64.
// Pipeline:
//   k1          : blocks 0,1 -> Taylor expm(M) / expm(64*M) (1 wave each, bf16 MFMA)
//                 blocks 2.. -> u = x @ (B*dt)^T  (bf16 MFMA, 64bt x 64n tiles)
//   scan_local  : 32 chunks x 64 steps, zero-init local scans -> F_c   (I+R MFMA step)
//   scan_chunks : 1 wave, 32-step scan over chunk boundaries with A_L -> P_c
//   scan_final  : re-run chunks with init P_c, write all states (T,B,N fp32)
//   out_proj    : out = states @ C^T + D*x  (bf16 MFMA, fp32 x-add)
// ws map (floats): [0]A_bar(4096) [4096]A_L(4096) [8192]F(32768) [40960]P(32768)
//                  [73728]u(2097152, layout (T,B,N)) [2170880]states(2097152) = 17.1 MB

#define H   1024
#define NS  64
#define NB  16
#define TT  2048
#define LCH 64
#define KCH 32

typedef __attribute__((ext_vector_type(8))) short bf16x8;
typedef __attribute__((ext_vector_type(4))) float f32x4;
typedef __attribute__((ext_vector_type(2))) unsigned int u32x2;

#define WS_ABAR 0
#define WS_AL   4096
#define WS_F    8192
#define WS_P    40960
#define WS_U    73728
#define WS_S    2170880

__device__ __forceinline__ unsigned short f2bf(float x) {
  union { float f; unsigned u; } v; v.f = x;
  unsigned r = (v.u + 0x7FFFu + ((v.u >> 16) & 1u)) >> 16;   // RNE
  return (unsigned short)r;
}

__device__ __forceinline__ bf16x8 packbf8(f32x4 a, f32x4 b) {
  bf16x8 r;
  r[0] = (short)f2bf(a[0]); r[1] = (short)f2bf(a[1]);
  r[2] = (short)f2bf(a[2]); r[3] = (short)f2bf(a[3]);
  r[4] = (short)f2bf(b[0]); r[5] = (short)f2bf(b[1]);
  r[6] = (short)f2bf(b[2]); r[7] = (short)f2bf(b[3]);
  return r;
}

__device__ __forceinline__ u32x2 packbf4(f32x4 v) {
  u32x2 r;
  r[0] = (unsigned)f2bf(v[0]) | ((unsigned)f2bf(v[1]) << 16);
  r[1] = (unsigned)f2bf(v[2]) | ((unsigned)f2bf(v[3]) << 16);
  return r;
}

__device__ __forceinline__ f32x4 mfma16(bf16x8 a, bf16x8 b, f32x4 c) {
  // D[m][n] = sum_k A[m][k]*B[k][n] + C.
  // A: lane holds A[m=lane&15][k=(lane>>4)*8+j]; B: B[k=(lane>>4)*8+j][n=lane&15];
  // C/D: col=lane&15, row=(lane>>4)*4+reg   (guide-verified layouts)
  return __builtin_amdgcn_mfma_f32_16x16x32_bf16(a, b, c, 0, 0, 0);
}

// ---------------- prep: E = expm(scale*A), 1 wave, Taylor-12 via bf16 MFMA ----------------
// Safe in bf16 because the identity is kept exact in fp32 (E = I + sum terms);
// only term_k @ (M/(k+1)) products (all tiny entries) go through MFMA.
__device__ void prep_block(const float* Ain, const float* ldt, float* ws, int which) {
  __shared__ float Mb[64 * 68];   // Mb[n][k] = M[k][n]  (B-operand view, +pad)
  __shared__ short Tl[64 * 72];   // current term, A-layout [m][k] bf16 (+pad, 16B-aligned rows)
  const int lane = threadIdx.x;
  const int cq = lane >> 4, cl = lane & 15;

  float s = 0.f;
  for (int j = 0; j < 16; ++j) s += expf(ldt[lane + j * 64]);
  for (int off = 32; off; off >>= 1) s += __shfl_down(s, off);
  float dtm = __shfl(s, 0) * (1.0f / 1024.0f);
  float scale = which ? dtm * (float)LCH : dtm;

  for (int idx = lane; idx < 4096; idx += 64) {
    int r = idx >> 6, c = idx & 63;
    float v = Ain[idx] * scale;
    Mb[c * 68 + r] = v;
    Tl[r * 72 + c] = (short)f2bf(v);       // term1 = M
  }

  float E[16][4];                           // C/D-layout accumulator, fp32
  for (int mt = 0; mt < 4; ++mt)
    for (int nt = 0; nt < 4; ++nt)
      for (int r = 0; r < 4; ++r) {
        int row = mt * 16 + cq * 4 + r, col = nt * 16 + cl;
        E[mt * 4 + nt][r] = (row == col ? 1.f : 0.f) + Ain[row * 64 + col] * scale;
      }

  __asm volatile("s_waitcnt lgkmcnt(0)" ::: "memory");

  for (int it = 2; it <= 12; ++it) {
    bf16x8 af[4][2];
    for (int mt = 0; mt < 4; ++mt)
      for (int kh = 0; kh < 2; ++kh)
        af[mt][kh] = *(const bf16x8*)&Tl[(mt * 16 + cl) * 72 + kh * 32 + cq * 8];
    float inv = 1.0f / (float)it;
    bf16x8 bfr[4][2];
    for (int nt = 0; nt < 4; ++nt)
      for (int kh = 0; kh < 2; ++kh) {
        const float* p = &Mb[(nt * 16 + cl) * 68 + kh * 32 + cq * 8];
        f32x4 a = *(const f32x4*)p;
        f32x4 b = *(const f32x4*)(p + 4);
        bfr[nt][kh] = packbf8(a * inv, b * inv);
      }
    f32x4 zero = {0.f, 0.f, 0.f, 0.f};
    f32x4 acc[16];
    for (int i = 0; i < 16; ++i) acc[i] = zero;
    for (int mt = 0; mt < 4; ++mt)
      for (int nt = 0; nt < 4; ++nt) {
        acc[mt * 4 + nt] = mfma16(af[mt][0], bfr[nt][0], acc[mt * 4 + nt]);
        acc[mt * 4 + nt] = mfma16(af[mt][1], bfr[nt][1], acc[mt * 4 + nt]);
      }
    __asm volatile("s_waitcnt lgkmcnt(0)" ::: "memory");
    for (int mt = 0; mt < 4; ++mt)
      for (int nt = 0; nt < 4; ++nt)
        for (int r = 0; r < 4; ++r) {
          float t = acc[mt * 4 + nt][r];
          E[mt * 4 + nt][r] += t;
          Tl[(mt * 16 + cq * 4 + r) * 72 + nt * 16 + cl] = (short)f2bf(t);
        }
    __asm volatile("s_waitcnt lgkmcnt(0)" ::: "memory");
  }

  float* dst = ws + (which ? WS_AL : WS_ABAR);
  for (int mt = 0; mt < 4; ++mt)
    for (int nt = 0; nt < 4; ++nt)
      for (int r = 0; r < 4; ++r)
        dst[(mt * 16 + cq * 4 + r) * 64 + nt * 16 + cl] = E[mt * 4 + nt][r];
}

// ---------------- u = x @ (B*dt)^T, 64bt x 64n per block, K-chunks of 32 ----------------
__device__ void gemm_u(const float* x, const float* Bm, const float* ldt, float* u2, int bid) {
  __shared__ short xl[64 * 40];   // [m][k] bf16, stride 40 (80B rows, 16B aligned)
  __shared__ short bl[64 * 40];   // [n][k] bf16 (B^T view: element = B[n][h]*dt[h])
  const int tid = threadIdx.x;
  const int bt0 = bid * 64;
  const int wid = tid >> 6, lane = tid & 63;
  const int cq = lane >> 4, cl = lane & 15;
  const int mst = tid >> 2, k0 = (tid & 3) * 8;

  f32x4 zero = {0.f, 0.f, 0.f, 0.f};
  f32x4 acc[4];
  for (int i = 0; i < 4; ++i) acc[i] = zero;

  const float* xrow = x + (long)(bt0 + mst) * H + k0;
  const float* brow = Bm + (long)mst * H + k0;

  for (int hc = 0; hc < 32; ++hc) {
    int h0 = hc * 32;
    f32x4 xa = *(const f32x4*)(xrow + h0);
    f32x4 xb = *(const f32x4*)(xrow + h0 + 4);
    f32x4 ba = *(const f32x4*)(brow + h0);
    f32x4 bb = *(const f32x4*)(brow + h0 + 4);
    f32x4 da, db;
    for (int j = 0; j < 4; ++j) {
      da[j] = expf(ldt[h0 + k0 + j]);
      db[j] = expf(ldt[h0 + k0 + 4 + j]);
    }
    *(bf16x8*)&xl[mst * 40 + k0] = packbf8(xa, xb);
    *(bf16x8*)&bl[mst * 40 + k0] = packbf8(ba * da, bb * db);
    __syncthreads();
    bf16x8 afr = *(const bf16x8*)&xl[(wid * 16 + cl) * 40 + cq * 8];
    for (int nt = 0; nt < 4; ++nt) {
      bf16x8 bfr = *(const bf16x8*)&bl[(nt * 16 + cl) * 40 + cq * 8];
      acc[nt] = mfma16(afr, bfr, acc[nt]);
    }
    __syncthreads();
  }
  for (int nt = 0; nt < 4; ++nt)
    for (int r = 0; r < 4; ++r) {
      int bt = bt0 + wid * 16 + cq * 4 + r;
      int t = bt & (TT - 1), b = bt >> 11;
      u2[(long)(t * 16 + b) * 64 + nt * 16 + cl] = acc[nt][r];
    }
}

__global__ __launch_bounds__(256) void k1(const float* x, const float* Ain, const float* Bm,
                                          const float* ldt, float* ws) {
  if (blockIdx.x < 2) {
    if (threadIdx.x < 64) prep_block(Ain, ldt, ws, blockIdx.x);
    return;
  }
  gemm_u(x, Bm, ldt, ws + WS_U, blockIdx.x - 2);
}

// ---------------- scan step: Z_new = (I+R) @ Z + U, transposed (Z is N x B) ----------------
__device__ __forceinline__ void load_RF(const float* Amat, bf16x8 Rf[4][2], int cq, int cl) {
  for (int mt = 0; mt < 4; ++mt)
    for (int kh = 0; kh < 2; ++kh) {
      int m = mt * 16 + cl;
      int kb = kh * 32 + cq * 8;
      f32x4 v0 = *(const f32x4*)&Amat[m * 64 + kb];
      f32x4 v1 = *(const f32x4*)&Amat[m * 64 + kb + 4];
      for (int j = 0; j < 4; ++j) {
        if (m == kb + j) v0[j] -= 1.f;          // R = A_bar - I
        if (m == kb + 4 + j) v1[j] -= 1.f;
      }
      Rf[mt][kh] = packbf8(v0, v1);
    }
}

// Single wave. Z[4] f32x4 in C/D layout: per lane state index i = tile*16+cq*4+reg, batch b=cl.
// Zl layout: [b][k] bf16, row stride 72 (144B, 16B-aligned). In-order DS pipe + asm barrier
// makes the write->read round-trip safe without s_barrier.
__device__ __forceinline__ void scan_step(f32x4 Z[4], const bf16x8 Rf[4][2], short* Zl,
                                          const f32x4 U[4], int cq, int cl) {
  for (int t = 0; t < 4; ++t)
    *(u32x2*)&Zl[cl * 72 + t * 16 + cq * 4] = packbf4(Z[t]);   // old Z -> bf16 LDS
  __asm volatile("s_waitcnt lgkmcnt(0)" ::: "memory");
  bf16x8 zf0 = *(const bf16x8*)&Zl[cl * 72 + cq * 8];
  bf16x8 zf1 = *(const bf16x8*)&Zl[cl * 72 + 32 + cq * 8];
  for (int t = 0; t < 4; ++t) Z[t] += U[t];                    // identity path + input, fp32
  for (int mt = 0; mt < 4; ++mt) {
    Z[mt] = mfma16(Rf[mt][0], zf0, Z[mt]);                     // += R @ Z_old
    Z[mt] = mfma16(Rf[mt][1], zf1, Z[mt]);
  }
}

__global__ __launch_bounds__(64) void scan_local_k(float* ws) {
  const float* Abar = ws + WS_ABAR;
  const float* u2 = ws + WS_U;
  float* F = ws + WS_F;
  __shared__ short Zl[16 * 72];
  const int lane = threadIdx.x, cq = lane >> 4, cl = lane & 15;
  const int c = blockIdx.x;
  bf16x8 Rf[4][2];
  load_RF(Abar, Rf, cq, cl);
  f32x4 zero = {0.f, 0.f, 0.f, 0.f};
  f32x4 Z[4], U[4], Un[4];
  for (int t = 0; t < 4; ++t) Z[t] = zero;
  const float* ub = u2 + (long)c * LCH * 1024 + cl * 64 + cq * 4;
  for (int t = 0; t < 4; ++t) U[t] = *(const f32x4*)(ub + t * 16);
  for (int ti = 0; ti < LCH; ++ti) {
    const float* un = ub + (ti + 1) * 1024;   // prefetch (last iter reads into ws scratch: harmless)
    for (int t = 0; t < 4; ++t) Un[t] = *(const f32x4*)(un + t * 16);
    scan_step(Z, Rf, Zl, U, cq, cl);
    for (int t = 0; t < 4; ++t) U[t] = Un[t];
  }
  for (int t = 0; t < 4; ++t)
    *(f32x4*)&F[(long)c * 1024 + cl * 64 + t * 16 + cq * 4] = Z[t];
}

__global__ __launch_bounds__(64) void scan_chunks_k(float* ws) {
  const float* AL = ws + WS_AL;
  const float* F = ws + WS_F;
  float* P = ws + WS_P;
  __shared__ short Zl[16 * 72];
  const int lane = threadIdx.x, cq = lane >> 4, cl = lane & 15;
  bf16x8 Rf[4][2];
  load_RF(AL, Rf, cq, cl);
  f32x4 zero = {0.f, 0.f, 0.f, 0.f};
  f32x4 Z[4], U[4];
  for (int t = 0; t < 4; ++t) Z[t] = zero;
  for (int c = 0; c < KCH; ++c) {
    long off = (long)c * 1024 + cl * 64 + cq * 4;
    for (int t = 0; t < 4; ++t) *(f32x4*)&P[off + t * 16] = Z[t];   // P_c before update
    for (int t = 0; t < 4; ++t) U[t] = *(const f32x4*)&F[off + t * 16];
    scan_step(Z, Rf, Zl, U, cq, cl);                                 // P_{c+1} = A_L P_c + F_c
  }
}

__global__ __launch_bounds__(64) void scan_final_k(float* ws) {
  const float* Abar = ws + WS_ABAR;
  const float* u2 = ws + WS_U;
  const float* P = ws + WS_P;
  float* S2 = ws + WS_S;
  __shared__ short Zl[16 * 72];
  const int lane = threadIdx.x, cq = lane >> 4, cl = lane & 15;
  const int c = blockIdx.x;
  bf16x8 Rf[4][2];
  load_RF(Abar, Rf, cq, cl);
  f32x4 Z[4], U[4], Un[4];
  long poff = (long)c * 1024 + cl * 64 + cq * 4;
  for (int t = 0; t < 4; ++t) Z[t] = *(const f32x4*)&P[poff + t * 16];
  const float* ub = u2 + (long)c * LCH * 1024 + cl * 64 + cq * 4;
  float* sb = S2 + (long)c * LCH * 1024 + cl * 64 + cq * 4;
  for (int t = 0; t < 4; ++t) U[t] = *(const f32x4*)(ub + t * 16);
  for (int ti = 0; ti < LCH; ++ti) {
    const float* un = ub + (ti + 1) * 1024;
    for (int t = 0; t < 4; ++t) Un[t] = *(const f32x4*)(un + t * 16);
    scan_step(Z, Rf, Zl, U, cq, cl);
    float* so = sb + ti * 1024;
    for (int t = 0; t < 4; ++t) *(f32x4*)(so + t * 16) = Z[t];       // state AFTER step t
    for (int t = 0; t < 4; ++t) U[t] = Un[t];
  }
}

// ---------------- out = states @ C^T + D*x, 64bt x 128h per block ----------------
__global__ __launch_bounds__(256) void out_proj_k(const float* ws, const float* Cm,
                                                  const float* Dv, const float* x, float* out) {
  const float* S2 = ws + WS_S;
  __shared__ short sl[64 * 72];    // states [m][k=n] bf16
  __shared__ short cls[128 * 72];  // C^T    [hcol][k=n] bf16 (= C[h][n])
  const int tid = threadIdx.x;
  const int bid = blockIdx.x;
  const int bt0 = (bid & 511) * 64;
  const int h0 = (bid >> 9) * 128;
  const int wid = tid >> 6, lane = tid & 63;
  const int cq = lane >> 4, cl = lane & 15;

  {
    int m = tid >> 2, k0 = (tid & 3) * 16;
    int bt = bt0 + m, t = bt & (TT - 1), b = bt >> 11;
    const float* sr = S2 + (long)(t * 16 + b) * 64 + k0;
    f32x4 a0 = *(const f32x4*)(sr);
    f32x4 a1 = *(const f32x4*)(sr + 4);
    f32x4 a2 = *(const f32x4*)(sr + 8);
    f32x4 a3 = *(const f32x4*)(sr + 12);
    *(bf16x8*)&sl[m * 72 + k0] = packbf8(a0, a1);
    *(bf16x8*)&sl[m * 72 + k0 + 8] = packbf8(a2, a3);

    int hl = tid >> 1, kc = (tid & 1) * 32;
    const float* cr = Cm + (long)(h0 + hl) * 64 + kc;
    f32x4 c0 = *(const f32x4*)(cr);
    f32x4 c1 = *(const f32x4*)(cr + 4);
    f32x4 c2 = *(const f32x4*)(cr + 8);
    f32x4 c3 = *(const f32x4*)(cr + 12);
    f32x4 c4 = *(const f32x4*)(cr + 16);
    f32x4 c5 = *(const f32x4*)(cr + 20);
    f32x4 c6 = *(const f32x4*)(cr + 24);
    f32x4 c7 = *(const f32x4*)(cr + 28);
    *(bf16x8*)&cls[hl * 72 + kc] = packbf8(c0, c1);
    *(bf16x8*)&cls[hl * 72 + kc + 8] = packbf8(c2, c3);
    *(bf16x8*)&cls[hl * 72 + kc + 16] = packbf8(c4, c5);
    *(bf16x8*)&cls[hl * 72 + kc + 24] = packbf8(c6, c7);
  }
  __syncthreads();

  bf16x8 af0 = *(const bf16x8*)&sl[(wid * 16 + cl) * 72 + cq * 8];
  bf16x8 af1 = *(const bf16x8*)&sl[(wid * 16 + cl) * 72 + 32 + cq * 8];
  f32x4 zero = {0.f, 0.f, 0.f, 0.f};
  for (int nt = 0; nt < 8; ++nt) {
    bf16x8 b0 = *(const bf16x8*)&cls[(nt * 16 + cl) * 72 + cq * 8];
    bf16x8 b1 = *(const bf16x8*)&cls[(nt * 16 + cl) * 72 + 32 + cq * 8];
    f32x4 acc = zero;
    acc = mfma16(af0, b0, acc);
    acc = mfma16(af1, b1, acc);
    int h = h0 + nt * 16 + cl;
    float d = Dv[h];
    for (int r = 0; r < 4; ++r) {
      long bt = bt0 + wid * 16 + cq * 4 + r;
      long idx = bt * H + h;
      out[idx] = acc[r] + d * x[idx];     // x-path kept fp32
    }
  }
}

extern "C" void kernel_launch(void* const* d_in, const int* in_sizes, int n_in,
                              void* d_out, int out_size, void* d_ws, size_t ws_size,
                              hipStream_t stream) {
  const float* x = (const float*)d_in[0];
  const float* A = (const float*)d_in[1];
  const float* Bm = (const float*)d_in[2];
  const float* Cm = (const float*)d_in[3];
  const float* Dv = (const float*)d_in[4];
  const float* ldt = (const float*)d_in[5];
  float* out = (float*)d_out;
  float* ws = (float*)d_ws;

  k1<<<dim3(2 + 512), dim3(256), 0, stream>>>(x, A, Bm, ldt, ws);
  scan_local_k<<<dim3(KCH), dim3(64), 0, stream>>>(ws);
  scan_chunks_k<<<dim3(1), dim3(64), 0, stream>>>(ws);
  scan_final_k<<<dim3(KCH), dim3(64), 0, stream>>>(ws);
  out_proj_k<<<dim3(4096), dim3(256), 0, stream>>>(ws, Cm, Dv, x, out);
}